// Round 3
// baseline (4096.821 us; speedup 1.0000x reference)
//
#include <hip/hip_runtime.h>
#include <hip/hip_bf16.h>
#include <stdint.h>

// GCN encoder: h = relu(A(x@W1)+b1); hagg = A h; [mu|ls] = hagg@[Wmu|Wls] + [bmu|bls]
// A = sym-normalized adjacency with self-loops. CSR-by-dst aggregation (one wave
// per node, register accumulation, 4-edge MLP unroll). GEMMs: fp32 vector, W-only
// LDS staging (32KB), A streamed via wave-broadcast global loads.

static inline size_t align_up(size_t x, size_t a) { return (x + a - 1) / a * a; }

// ---------------- edge decode (int32 vs int64 robustness) ----------------

__global__ void detect_i64_kernel(const int* __restrict__ ei, int nwords_check, int* __restrict__ flag) {
    __shared__ int any_nz;
    if (threadIdx.x == 0) any_nz = 0;
    __syncthreads();
    int nz = 0;
    for (int i = threadIdx.x; i < nwords_check; i += blockDim.x) {
        if (ei[2 * i + 1] != 0) nz = 1;
    }
    if (nz) atomicOr(&any_nz, 1);
    __syncthreads();
    if (threadIdx.x == 0) flag[0] = any_nz ? 0 : 1;  // all-zero high words => int64
}

__device__ inline int load_idx(const void* ei, const int* flag, size_t pos, int n) {
    int v;
    if (flag[0]) v = (int)((const long long*)ei)[pos];
    else         v = ((const int*)ei)[pos];
    return (v < 0) ? 0 : (v >= n ? n - 1 : v);
}

// ---------------- degree count (int atomics, cheap) ----------------

__global__ void deg_count_kernel(const void* __restrict__ ei, const int* __restrict__ flag,
                                 int* __restrict__ deg, int E, int n) {
    int i = blockIdx.x * blockDim.x + threadIdx.x;
    if (i >= E) return;
    int d = load_idx(ei, flag, (size_t)E + i, n);
    atomicAdd(&deg[d], 1);
}

__global__ void deg_finish_kernel(const int* __restrict__ deg, float* __restrict__ dis, int n) {
    int i = blockIdx.x * blockDim.x + threadIdx.x;
    if (i < n) dis[i] = rsqrtf((float)deg[i] + 1.0f);  // +1 = self loop
}

// ---------------- exclusive prefix scan (3 phase) ----------------

__global__ void scan_blocks_kernel(const int* __restrict__ deg, int* __restrict__ excl,
                                   int* __restrict__ bsum, int n) {
    __shared__ int tmp[256];
    int i = blockIdx.x * 256 + threadIdx.x;
    int v = (i < n) ? deg[i] : 0;
    tmp[threadIdx.x] = v;
    __syncthreads();
    for (int off = 1; off < 256; off <<= 1) {
        int t = (threadIdx.x >= off) ? tmp[threadIdx.x - off] : 0;
        __syncthreads();
        tmp[threadIdx.x] += t;
        __syncthreads();
    }
    if (i < n) excl[i] = tmp[threadIdx.x] - v;
    if (threadIdx.x == 255) bsum[blockIdx.x] = tmp[255];
}

__global__ void scan_sums_kernel(int* __restrict__ bs, int nb) {
    __shared__ int tmp[1024];
    int t = threadIdx.x;
    if (nb <= 1024) {
        int v = (t < nb) ? bs[t] : 0;
        tmp[t] = v;
        __syncthreads();
        for (int off = 1; off < 1024; off <<= 1) {
            int u = (t >= off) ? tmp[t - off] : 0;
            __syncthreads();
            tmp[t] += u;
            __syncthreads();
        }
        if (t < nb) bs[t] = tmp[t] - v;  // exclusive
    } else if (t == 0) {
        int acc = 0;
        for (int i = 0; i < nb; ++i) { int v = bs[i]; bs[i] = acc; acc += v; }
    }
}

__global__ void scan_add_kernel(int* __restrict__ excl, const int* __restrict__ bsum,
                                int* __restrict__ cursor, int n) {
    int i = blockIdx.x * 256 + threadIdx.x;
    if (i < n) {
        int v = excl[i] + bsum[blockIdx.x];
        excl[i] = v;     // row_ptr (begin)
        cursor[i] = v;   // scatter cursor; after scatter == row end
    }
}

// ---------------- CSR scatter (int atomics on cursors) ----------------

__global__ void scatter_kernel(const void* __restrict__ ei, const int* __restrict__ flag,
                               int* __restrict__ cursor, int* __restrict__ csr_src,
                               int E, int n) {
    int i = blockIdx.x * blockDim.x + threadIdx.x;
    if (i >= E) return;
    int s = load_idx(ei, flag, i, n);
    int d = load_idx(ei, flag, (size_t)E + i, n);
    int pos = atomicAdd(&cursor[d], 1);
    csr_src[pos] = s;
}

// ---------------- fused CSR aggregation (one wave per node) ----------------
// out[v] = act( sum_e dis[s]*dis[v] * hin[s] + dis[v]^2 * hin[v] + bias )
// 64 lanes x float2 = 128 features; 4-edge unroll for memory-level parallelism.

__global__ __launch_bounds__(256) void csr_agg_kernel(
        const float* __restrict__ hin, const int* __restrict__ row_beg,
        const int* __restrict__ row_end, const int* __restrict__ csr_src,
        const float* __restrict__ dis, const float* __restrict__ bias,
        float* __restrict__ out, int n, int relu) {
    int node = blockIdx.x * 4 + (threadIdx.x >> 6);
    if (node >= n) return;
    int lane = threadIdx.x & 63;
    int beg = row_beg[node], end = row_end[node];
    float dv = dis[node];

    float2 a0 = make_float2(0.f, 0.f), a1 = a0, a2 = a0, a3 = a0;
    int e = beg;
    for (; e + 3 < end; e += 4) {
        int s0 = csr_src[e + 0], s1 = csr_src[e + 1];
        int s2 = csr_src[e + 2], s3 = csr_src[e + 3];
        float w0 = dis[s0] * dv, w1 = dis[s1] * dv;
        float w2 = dis[s2] * dv, w3 = dis[s3] * dv;
        float2 v0 = *(const float2*)&hin[(size_t)s0 * 128 + lane * 2];
        float2 v1 = *(const float2*)&hin[(size_t)s1 * 128 + lane * 2];
        float2 v2 = *(const float2*)&hin[(size_t)s2 * 128 + lane * 2];
        float2 v3 = *(const float2*)&hin[(size_t)s3 * 128 + lane * 2];
        a0.x += v0.x * w0; a0.y += v0.y * w0;
        a1.x += v1.x * w1; a1.y += v1.y * w1;
        a2.x += v2.x * w2; a2.y += v2.y * w2;
        a3.x += v3.x * w3; a3.y += v3.y * w3;
    }
    for (; e < end; ++e) {
        int s = csr_src[e];
        float w = dis[s] * dv;
        float2 v = *(const float2*)&hin[(size_t)s * 128 + lane * 2];
        a0.x += v.x * w; a0.y += v.y * w;
    }
    float ds = dv * dv;
    float2 self = *(const float2*)&hin[(size_t)node * 128 + lane * 2];
    float2 acc;
    acc.x = (a0.x + a1.x) + (a2.x + a3.x) + ds * self.x;
    acc.y = (a0.y + a1.y) + (a2.y + a3.y) + ds * self.y;
    if (bias) {
        float2 bb = *(const float2*)&bias[lane * 2];
        acc.x += bb.x; acc.y += bb.y;
    }
    if (relu) { acc.x = fmaxf(acc.x, 0.0f); acc.y = fmaxf(acc.y, 0.0f); }
    *(float2*)&out[(size_t)node * 128 + lane * 2] = acc;
}

// ---------------- dense GEMM (fp32 vector, K=128, 128 cols) ----------------
// C[:, 0:64] from WA (+biasA) -> outA; C[:, 64:128] from WB (+biasB) -> outB.
// W staged in LDS in two 64-row K halves (32KB). A streamed from global:
// each A-row chunk is read by a 32-lane tx-group at the same address
// (wave-broadcast, L1-served). No A staging -> only 2 barriers per half.

__global__ __launch_bounds__(256, 4) void gemm_kernel(
        const float* __restrict__ A,
        const float* __restrict__ WA, const float* __restrict__ WB, int wstride,
        const float* __restrict__ biasA, const float* __restrict__ biasB,
        float* __restrict__ outA, int ostrideA,
        float* __restrict__ outB, int ostrideB, int n) {
    __shared__ float ws[64 * 128];
    const int tid = threadIdx.x;
    const int brow = blockIdx.x * 64;
    const int rows = min(64, n - brow);
    const int tx = tid & 31, ty = tid >> 5;
    const int j0 = tx * 4, r0 = ty * 8;

    // row pointers (clamped for the ragged last block; stores are guarded)
    const float* arow[8];
#pragma unroll
    for (int i = 0; i < 8; ++i) {
        int rr = min(r0 + i, rows - 1);
        arow[i] = A + (size_t)(brow + rr) * 128;
    }

    float acc[8][4] = {};

    for (int kh = 0; kh < 2; ++kh) {
        // stage W[kh*64 .. kh*64+63][0..127] into LDS (cols<64 from WA, else WB)
        for (int i = tid; i < 2048; i += 256) {
            int k = i >> 5;
            int c = (i & 31) * 4;
            const float* src = (c < 64)
                ? (WA + (size_t)(kh * 64 + k) * wstride + c)
                : (WB + (size_t)(kh * 64 + k) * wstride + (c - 64));
            ((float4*)ws)[i] = *(const float4*)src;
        }
        __syncthreads();
#pragma unroll
        for (int kk = 0; kk < 64; kk += 4) {
            float4 w0 = *(const float4*)&ws[(kk + 0) * 128 + j0];
            float4 w1 = *(const float4*)&ws[(kk + 1) * 128 + j0];
            float4 w2 = *(const float4*)&ws[(kk + 2) * 128 + j0];
            float4 w3 = *(const float4*)&ws[(kk + 3) * 128 + j0];
#pragma unroll
            for (int i = 0; i < 8; ++i) {
                float4 xv = *(const float4*)&arow[i][kh * 64 + kk];
                acc[i][0] += xv.x * w0.x + xv.y * w1.x + xv.z * w2.x + xv.w * w3.x;
                acc[i][1] += xv.x * w0.y + xv.y * w1.y + xv.z * w2.y + xv.w * w3.y;
                acc[i][2] += xv.x * w0.z + xv.y * w1.z + xv.z * w2.z + xv.w * w3.z;
                acc[i][3] += xv.x * w0.w + xv.y * w1.w + xv.z * w2.w + xv.w * w3.w;
            }
        }
        __syncthreads();
    }

    float4 bv = make_float4(0.f, 0.f, 0.f, 0.f);
    if (biasA) {
        bv = (tx < 16) ? *(const float4*)&biasA[j0]
                       : *(const float4*)&biasB[j0 - 64];
    }
#pragma unroll
    for (int i = 0; i < 8; ++i) {
        int r = r0 + i;
        if (r < rows) {
            float4 st = make_float4(acc[i][0] + bv.x, acc[i][1] + bv.y,
                                    acc[i][2] + bv.z, acc[i][3] + bv.w);
            size_t gr = (size_t)(brow + r);
            if (tx < 16)
                *(float4*)&outA[gr * ostrideA + j0] = st;
            else
                *(float4*)&outB[gr * ostrideB + (j0 - 64)] = st;
        }
    }
}

// ---------------- launcher ----------------

extern "C" void kernel_launch(void* const* d_in, const int* in_sizes, int n_in,
                              void* d_out, int out_size, void* d_ws, size_t ws_size,
                              hipStream_t stream) {
    const float* x   = (const float*)d_in[0];
    const void*  ei  = d_in[1];
    const float* W1  = (const float*)d_in[2];
    const float* b1  = (const float*)d_in[3];
    const float* Wmu = (const float*)d_in[4];
    const float* bmu = (const float*)d_in[5];
    const float* Wls = (const float*)d_in[6];
    const float* bls = (const float*)d_in[7];

    const int n = in_sizes[0] / 128;
    const int E = in_sizes[1] / 2;

    float* out   = (float*)d_out;
    float* outMu = out;
    float* outLs = out + (size_t)n * 64;

    char* w = (char*)d_ws;
    auto alloc = [&](size_t bytes) { char* p = w; w += align_up(bytes, 256); return p; };
    int*   flag    = (int*)  alloc(256);
    int*   deg     = (int*)  alloc((size_t)n * 4);
    int*   row_beg = (int*)  alloc((size_t)n * 4);
    int*   cursor  = (int*)  alloc((size_t)n * 4);   // after scatter: row end
    int*   bsum    = (int*)  alloc(1024 * 4);
    float* dis     = (float*)alloc((size_t)n * 4);
    int*   csr_src = (int*)  alloc((size_t)E * 4);
    float* bufA    = (float*)alloc((size_t)n * 128 * 4);  // x@W1, later hagg
    float* bufB    = (float*)alloc((size_t)n * 128 * 4);  // h

    hipMemsetAsync(deg, 0, (size_t)n * 4, stream);

    // ---- graph preprocessing: CSR by dst ----
    detect_i64_kernel<<<1, 256, 0, stream>>>((const int*)ei, 1024, flag);
    deg_count_kernel<<<(E + 255) / 256, 256, 0, stream>>>(ei, flag, deg, E, n);
    deg_finish_kernel<<<(n + 255) / 256, 256, 0, stream>>>(deg, dis, n);
    const int nb = (n + 255) / 256;
    scan_blocks_kernel<<<nb, 256, 0, stream>>>(deg, row_beg, bsum, n);
    scan_sums_kernel<<<1, 1024, 0, stream>>>(bsum, nb);
    scan_add_kernel<<<nb, 256, 0, stream>>>(row_beg, bsum, cursor, n);
    scatter_kernel<<<(E + 255) / 256, 256, 0, stream>>>(ei, flag, cursor, csr_src, E, n);

    const int gblocks = (n + 63) / 64;

    // ---- layer 1: h = relu(A(x@W1) + b1) ----
    gemm_kernel<<<gblocks, 256, 0, stream>>>(x, W1, W1 + 64, 128, nullptr, nullptr,
                                             bufA, 128, bufA + 64, 128, n);
    csr_agg_kernel<<<(n + 3) / 4, 256, 0, stream>>>(bufA, row_beg, cursor, csr_src,
                                                    dis, b1, bufB, n, 1);

    // ---- layer 2+3: hagg = A h; [mu|ls] = hagg @ [Wmu|Wls] + [bmu|bls] ----
    csr_agg_kernel<<<(n + 3) / 4, 256, 0, stream>>>(bufB, row_beg, cursor, csr_src,
                                                    dis, nullptr, bufA, n, 0);
    gemm_kernel<<<gblocks, 256, 0, stream>>>(bufA, Wmu, Wls, 64, bmu, bls,
                                             outMu, 64, outLs, 64, n);
}

// Round 4
// 407.897 us; speedup vs baseline: 10.0438x; 10.0438x over previous
//
#include <hip/hip_runtime.h>
#include <hip/hip_bf16.h>
#include <stdint.h>

// GCN encoder: h = relu(A(x@W1)+b1); hagg = A h; [mu|ls] = hagg@[Wmu|Wls] + [bmu|bls]
// A = sym-normalized adjacency with self-loops.
// - GEMMs: bf16 MFMA (16x16x32), W transposed->bf16 in LDS (row pad 272B, 2-way alias only),
//   A-fragments streamed from global (8 consecutive K elems per lane).
// - Intermediates (xW, h, hagg) stored bf16 -> halves the edge-gather traffic.
// - Aggregation: CSR-by-dst, one wave per node, fp32 register accumulation, 4-edge unroll.

static inline size_t align_up(size_t x, size_t a) { return (x + a - 1) / a * a; }

typedef __attribute__((ext_vector_type(8))) short short8;
typedef __attribute__((ext_vector_type(4))) float f32x4;

__device__ inline unsigned short f2bf(float f) {
    unsigned u = __float_as_uint(f);
    unsigned r = (u + 0x7FFFu + ((u >> 16) & 1u)) >> 16;  // RNE
    return (unsigned short)r;
}
__device__ inline float bf2f(unsigned v16) {
    return __uint_as_float(v16 << 16);
}

// ---------------- edge decode (int32 vs int64 robustness) ----------------

__global__ void detect_i64_kernel(const int* __restrict__ ei, int nwords_check, int* __restrict__ flag) {
    __shared__ int any_nz;
    if (threadIdx.x == 0) any_nz = 0;
    __syncthreads();
    int nz = 0;
    for (int i = threadIdx.x; i < nwords_check; i += blockDim.x) {
        if (ei[2 * i + 1] != 0) nz = 1;
    }
    if (nz) atomicOr(&any_nz, 1);
    __syncthreads();
    if (threadIdx.x == 0) flag[0] = any_nz ? 0 : 1;  // all-zero high words => int64
}

__device__ inline int load_idx(const void* ei, const int* flag, size_t pos, int n) {
    int v;
    if (flag[0]) v = (int)((const long long*)ei)[pos];
    else         v = ((const int*)ei)[pos];
    return (v < 0) ? 0 : (v >= n ? n - 1 : v);
}

// ---------------- degree count ----------------

__global__ void deg_count_kernel(const void* __restrict__ ei, const int* __restrict__ flag,
                                 int* __restrict__ deg, int E, int n) {
    int i = blockIdx.x * blockDim.x + threadIdx.x;
    if (i >= E) return;
    int d = load_idx(ei, flag, (size_t)E + i, n);
    atomicAdd(&deg[d], 1);
}

__global__ void deg_finish_kernel(const int* __restrict__ deg, float* __restrict__ dis, int n) {
    int i = blockIdx.x * blockDim.x + threadIdx.x;
    if (i < n) dis[i] = rsqrtf((float)deg[i] + 1.0f);  // +1 = self loop
}

// ---------------- exclusive prefix scan (3 phase) ----------------

__global__ void scan_blocks_kernel(const int* __restrict__ deg, int* __restrict__ excl,
                                   int* __restrict__ bsum, int n) {
    __shared__ int tmp[256];
    int i = blockIdx.x * 256 + threadIdx.x;
    int v = (i < n) ? deg[i] : 0;
    tmp[threadIdx.x] = v;
    __syncthreads();
    for (int off = 1; off < 256; off <<= 1) {
        int t = (threadIdx.x >= off) ? tmp[threadIdx.x - off] : 0;
        __syncthreads();
        tmp[threadIdx.x] += t;
        __syncthreads();
    }
    if (i < n) excl[i] = tmp[threadIdx.x] - v;
    if (threadIdx.x == 255) bsum[blockIdx.x] = tmp[255];
}

__global__ void scan_sums_kernel(int* __restrict__ bs, int nb) {
    __shared__ int tmp[1024];
    int t = threadIdx.x;
    if (nb <= 1024) {
        int v = (t < nb) ? bs[t] : 0;
        tmp[t] = v;
        __syncthreads();
        for (int off = 1; off < 1024; off <<= 1) {
            int u = (t >= off) ? tmp[t - off] : 0;
            __syncthreads();
            tmp[t] += u;
            __syncthreads();
        }
        if (t < nb) bs[t] = tmp[t] - v;  // exclusive
    } else if (t == 0) {
        int acc = 0;
        for (int i = 0; i < nb; ++i) { int v = bs[i]; bs[i] = acc; acc += v; }
    }
}

__global__ void scan_add_kernel(int* __restrict__ excl, const int* __restrict__ bsum,
                                int* __restrict__ cursor, int n) {
    int i = blockIdx.x * 256 + threadIdx.x;
    if (i < n) {
        int v = excl[i] + bsum[blockIdx.x];
        excl[i] = v;     // row_ptr (begin)
        cursor[i] = v;   // scatter cursor; after scatter == row end
    }
}

// ---------------- CSR scatter (int atomics on cursors) ----------------

__global__ void scatter_kernel(const void* __restrict__ ei, const int* __restrict__ flag,
                               int* __restrict__ cursor, int* __restrict__ csr_src,
                               int E, int n) {
    int i = blockIdx.x * blockDim.x + threadIdx.x;
    if (i >= E) return;
    int s = load_idx(ei, flag, i, n);
    int d = load_idx(ei, flag, (size_t)E + i, n);
    int pos = atomicAdd(&cursor[d], 1);
    csr_src[pos] = s;
}

// ---------------- weight prep: transpose to [N][K] bf16 ----------------

__global__ void prep_weights_kernel(const float* __restrict__ W1,
                                    const float* __restrict__ Wmu,
                                    const float* __restrict__ Wls,
                                    unsigned short* __restrict__ Wt1,
                                    unsigned short* __restrict__ Wtcat) {
    int idx = blockIdx.x * 256 + threadIdx.x;
    if (idx < 16384) {
        int c = idx >> 7, k = idx & 127;
        Wt1[c * 128 + k] = f2bf(W1[k * 128 + c]);
    } else if (idx < 32768) {
        int i = idx - 16384;
        int j = i >> 7, k = i & 127;
        float v = (j < 64) ? Wmu[k * 64 + j] : Wls[k * 64 + (j - 64)];
        Wtcat[j * 128 + k] = f2bf(v);
    }
}

// ---------------- MFMA GEMM: [n x 128] @ [128 x 128] ----------------
// MODE 0: A fp32, out bf16 [n][128], no bias (gemm1; bias fused into agg1)
// MODE 1: A bf16, out fp32 split outA(cols 0..63)+outB(64..127), bias biasA/biasB
// 256 thr = 4 waves; wave handles 16 rows x 128 cols = 8 col-tiles x 4 K-chunks.

template <int MODE>
__global__ __launch_bounds__(256) void mfma_gemm_kernel(
        const void* __restrict__ Ax, const unsigned short* __restrict__ Wt,
        const float* __restrict__ biasA, const float* __restrict__ biasB,
        void* __restrict__ outA, void* __restrict__ outB, int n) {
    __shared__ unsigned short ws[128 * 136];  // row stride 136 elems (272B): kills bank conflicts
    const int tid = threadIdx.x;
    const int wave = tid >> 6, lane = tid & 63;
    const int brow = blockIdx.x * 64 + wave * 16;
    const int lr = lane & 15;   // A-row / B-col within 16-tile
    const int kg = lane >> 4;   // k-group 0..3
    const int k0 = kg * 8;

    // stage Wt (bf16 [128][128]) -> LDS, 16B chunks, conflict-free
    for (int i = tid; i < 2048; i += 256) {
        int r = i >> 4, ci = i & 15;
        *(short8*)&ws[r * 136 + ci * 8] = *(const short8*)&Wt[r * 128 + ci * 8];
    }
    __syncthreads();

    int arow = brow + lr;
    if (arow >= n) arow = n - 1;  // clamp loads; stores guarded

    f32x4 acc[8];
#pragma unroll
    for (int t = 0; t < 8; ++t) acc[t] = (f32x4){0.f, 0.f, 0.f, 0.f};

#pragma unroll
    for (int c = 0; c < 4; ++c) {
        short8 a;
        if (MODE == 0) {
            const float* ap = (const float*)Ax + (size_t)arow * 128 + c * 32 + k0;
            float4 lo = *(const float4*)ap;
            float4 hi = *(const float4*)(ap + 4);
            a[0] = (short)f2bf(lo.x); a[1] = (short)f2bf(lo.y);
            a[2] = (short)f2bf(lo.z); a[3] = (short)f2bf(lo.w);
            a[4] = (short)f2bf(hi.x); a[5] = (short)f2bf(hi.y);
            a[6] = (short)f2bf(hi.z); a[7] = (short)f2bf(hi.w);
        } else {
            a = *(const short8*)((const unsigned short*)Ax + (size_t)arow * 128 + c * 32 + k0);
        }
#pragma unroll
        for (int t = 0; t < 8; ++t) {
            short8 b = *(const short8*)&ws[(t * 16 + lr) * 136 + c * 32 + k0];
            acc[t] = __builtin_amdgcn_mfma_f32_16x16x32_bf16(a, b, acc[t], 0, 0, 0);
        }
    }

    // C/D layout (m89): col = lane&15, row = (lane>>4)*4 + reg
    if (MODE == 0) {
        unsigned short* out = (unsigned short*)outA;
#pragma unroll
        for (int t = 0; t < 8; ++t) {
            int col = t * 16 + lr;
#pragma unroll
            for (int r = 0; r < 4; ++r) {
                int row = brow + kg * 4 + r;
                if (row < n) out[(size_t)row * 128 + col] = f2bf(acc[t][r]);
            }
        }
    } else {
        float* oA = (float*)outA;
        float* oB = (float*)outB;
#pragma unroll
        for (int t = 0; t < 8; ++t) {
            int col = t * 16 + lr;
            float bv = (col < 64) ? biasA[col] : biasB[col - 64];
#pragma unroll
            for (int r = 0; r < 4; ++r) {
                int row = brow + kg * 4 + r;
                if (row < n) {
                    float v = acc[t][r] + bv;
                    if (col < 64) oA[(size_t)row * 64 + col] = v;
                    else          oB[(size_t)row * 64 + (col - 64)] = v;
                }
            }
        }
    }
}

// ---------------- fused CSR aggregation (one wave per node, bf16 in/out) ----------------
// out[v] = act( sum_e dis[s]*dis[v]*hin[s] + dis[v]^2*hin[v] + bias )
// 64 lanes x 2 bf16 features; fp32 accumulation; 4-edge unroll for MLP.

__global__ __launch_bounds__(256) void csr_agg_kernel(
        const unsigned short* __restrict__ hin, const int* __restrict__ row_beg,
        const int* __restrict__ row_end, const int* __restrict__ csr_src,
        const float* __restrict__ dis, const float* __restrict__ bias,
        unsigned short* __restrict__ out, int n, int relu) {
    int node = blockIdx.x * 4 + (threadIdx.x >> 6);
    if (node >= n) return;
    int lane = threadIdx.x & 63;
    int f = lane * 2;
    int beg = row_beg[node], end = row_end[node];
    float dv = dis[node];

    float ax0 = 0.f, ay0 = 0.f, ax1 = 0.f, ay1 = 0.f;
    float ax2 = 0.f, ay2 = 0.f, ax3 = 0.f, ay3 = 0.f;
    int e = beg;
    for (; e + 3 < end; e += 4) {
        int s0 = csr_src[e + 0], s1 = csr_src[e + 1];
        int s2 = csr_src[e + 2], s3 = csr_src[e + 3];
        float w0 = dis[s0] * dv, w1 = dis[s1] * dv;
        float w2 = dis[s2] * dv, w3 = dis[s3] * dv;
        unsigned v0 = *(const unsigned*)&hin[(size_t)s0 * 128 + f];
        unsigned v1 = *(const unsigned*)&hin[(size_t)s1 * 128 + f];
        unsigned v2 = *(const unsigned*)&hin[(size_t)s2 * 128 + f];
        unsigned v3 = *(const unsigned*)&hin[(size_t)s3 * 128 + f];
        ax0 += bf2f(v0 & 0xffffu) * w0; ay0 += bf2f(v0 >> 16) * w0;
        ax1 += bf2f(v1 & 0xffffu) * w1; ay1 += bf2f(v1 >> 16) * w1;
        ax2 += bf2f(v2 & 0xffffu) * w2; ay2 += bf2f(v2 >> 16) * w2;
        ax3 += bf2f(v3 & 0xffffu) * w3; ay3 += bf2f(v3 >> 16) * w3;
    }
    for (; e < end; ++e) {
        int s = csr_src[e];
        float w = dis[s] * dv;
        unsigned v = *(const unsigned*)&hin[(size_t)s * 128 + f];
        ax0 += bf2f(v & 0xffffu) * w; ay0 += bf2f(v >> 16) * w;
    }
    float ds = dv * dv;
    unsigned sv = *(const unsigned*)&hin[(size_t)node * 128 + f];
    float accx = (ax0 + ax1) + (ax2 + ax3) + ds * bf2f(sv & 0xffffu);
    float accy = (ay0 + ay1) + (ay2 + ay3) + ds * bf2f(sv >> 16);
    if (bias) {
        accx += bias[f];
        accy += bias[f + 1];
    }
    if (relu) { accx = fmaxf(accx, 0.f); accy = fmaxf(accy, 0.f); }
    unsigned o = (unsigned)f2bf(accx) | ((unsigned)f2bf(accy) << 16);
    *(unsigned*)&out[(size_t)node * 128 + f] = o;
}

// ---------------- launcher ----------------

extern "C" void kernel_launch(void* const* d_in, const int* in_sizes, int n_in,
                              void* d_out, int out_size, void* d_ws, size_t ws_size,
                              hipStream_t stream) {
    const float* x   = (const float*)d_in[0];
    const void*  ei  = d_in[1];
    const float* W1  = (const float*)d_in[2];
    const float* b1  = (const float*)d_in[3];
    const float* Wmu = (const float*)d_in[4];
    const float* bmu = (const float*)d_in[5];
    const float* Wls = (const float*)d_in[6];
    const float* bls = (const float*)d_in[7];

    const int n = in_sizes[0] / 128;
    const int E = in_sizes[1] / 2;

    float* out   = (float*)d_out;
    float* outMu = out;
    float* outLs = out + (size_t)n * 64;

    char* w = (char*)d_ws;
    auto alloc = [&](size_t bytes) { char* p = w; w += align_up(bytes, 256); return p; };
    int*            flag    = (int*)           alloc(256);
    int*            deg     = (int*)           alloc((size_t)n * 4);
    int*            row_beg = (int*)           alloc((size_t)n * 4);
    int*            cursor  = (int*)           alloc((size_t)n * 4);  // after scatter: row end
    int*            bsum    = (int*)           alloc(1024 * 4);
    float*          dis     = (float*)         alloc((size_t)n * 4);
    int*            csr_src = (int*)           alloc((size_t)E * 4);
    unsigned short* Wt1     = (unsigned short*)alloc(128 * 128 * 2);
    unsigned short* Wtcat   = (unsigned short*)alloc(128 * 128 * 2);
    unsigned short* xW      = (unsigned short*)alloc((size_t)n * 128 * 2);  // x@W1 (bf16)
    unsigned short* h       = (unsigned short*)alloc((size_t)n * 128 * 2);  // relu(A xW + b1)
    unsigned short* hagg    = (unsigned short*)alloc((size_t)n * 128 * 2);  // A h

    hipMemsetAsync(deg, 0, (size_t)n * 4, stream);

    // ---- graph preprocessing: CSR by dst ----
    detect_i64_kernel<<<1, 256, 0, stream>>>((const int*)ei, 1024, flag);
    deg_count_kernel<<<(E + 255) / 256, 256, 0, stream>>>(ei, flag, deg, E, n);
    deg_finish_kernel<<<(n + 255) / 256, 256, 0, stream>>>(deg, dis, n);
    const int nb = (n + 255) / 256;
    scan_blocks_kernel<<<nb, 256, 0, stream>>>(deg, row_beg, bsum, n);
    scan_sums_kernel<<<1, 1024, 0, stream>>>(bsum, nb);
    scan_add_kernel<<<nb, 256, 0, stream>>>(row_beg, bsum, cursor, n);
    scatter_kernel<<<(E + 255) / 256, 256, 0, stream>>>(ei, flag, cursor, csr_src, E, n);
    prep_weights_kernel<<<128, 256, 0, stream>>>(W1, Wmu, Wls, Wt1, Wtcat);

    const int gblocks = (n + 63) / 64;

    // ---- layer 1: h = relu(A(x@W1) + b1) ----
    mfma_gemm_kernel<0><<<gblocks, 256, 0, stream>>>(x, Wt1, nullptr, nullptr, xW, nullptr, n);
    csr_agg_kernel<<<(n + 3) / 4, 256, 0, stream>>>(xW, row_beg, cursor, csr_src,
                                                    dis, b1, h, n, 1);

    // ---- layer 2+3: hagg = A h; [mu|ls] = hagg @ [Wmu|Wls] + [bmu|bls] ----
    csr_agg_kernel<<<(n + 3) / 4, 256, 0, stream>>>(h, row_beg, cursor, csr_src,
                                                    dis, nullptr, hagg, n, 0);
    mfma_gemm_kernel<1><<<gblocks, 256, 0, stream>>>(hagg, Wtcat, bmu, bls, outMu, outLs, n);
}